// Round 13
// baseline (30.613 us; speedup 1.0000x reference)
//
#include <hip/hip_runtime.h>
#include <math.h>

#define NB 16          // batch
#define NT 512         // time
#define NC 32          // channels
#define NW 128         // window
#define TILE_T 32
#define NTILES (NT / TILE_T)        // 16
#define NBLK (NB * NTILES)          // 256 blocks -> one per CU, all co-resident
#define NROWS (TILE_T + NW)         // 160 real rows staged
#define PADROWS 169                 // + 9 zero rows (max read row = 168)
#define NTR 25                      // transition taps
#define WIN_MIN_F 2.0f
#define WIN_RANGE_F 62.0f

typedef float v2f __attribute__((ext_vector_type(2)));

__device__ __forceinline__ float fast_sigmoid_neg(float a) {
    // sigmoid(-a) = 1/(1+exp(a))
    return __builtin_amdgcn_rcpf(1.0f + __expf(a));
}

__global__ __launch_bounds__(256) void feat_fused(
    const float* __restrict__ x,
    const float* __restrict__ series,
    const int*   __restrict__ indices,
    const float* __restrict__ rwm,
    const float* __restrict__ rws,
    const float* __restrict__ gm, const float* __restrict__ bm,
    const float* __restrict__ gs, const float* __restrict__ bs,
    float* __restrict__ partials,          // NBLK * 128 floats in ws
    unsigned int* __restrict__ ctr,        // arrive counter (memset to 0 per call)
    float* __restrict__ out)
{
    // all 2D LDS arrays are [row][c] stride 32 -> bank = f(c) only -> conflict-free
    __shared__ __align__(16) float s_x[PADROWS * NC];   // 21.6 KB series tile (+zero pad)
    __shared__ __align__(16) v2f   s_P[NROWS * NC];     // 40 KB prefix sums (P1=x, P2=x^2)
    __shared__ __align__(16) v2f   s_wt[NTR * NC];      // 6.4 KB transition weights (w1,w2)
    __shared__ float s_win[2 * NC];
    __shared__ int   s_wsi[2 * NC];
    __shared__ __align__(16) float s_red[1024];   // scan arena / stats / partial-reduce
    __shared__ __align__(16) float s_sums[128];
    __shared__ __align__(16) float s_coef[128];   // A1,B1,A2,B2

    const int tid = threadIdx.x;
    const int blk = blockIdx.x;
    const int b   = blk >> 4;
    const int tt  = blk & 15;
    const int t0  = tt * TILE_T;
    const int start = indices[2 * b];

    // ---- BN-independent pass-through: out[:, :, 0:32] = x ----
    {
        const int row = b * NT + t0 + (tid >> 3);
        const int q = tid & 7;
        ((float4*)out)[row * 24 + q] = ((const float4*)x)[row * 8 + q];
    }

    // ---- per-channel window size + transition start ws = int(115 - win) ----
    if (tid < 2 * NC) {
        const int c = tid & 31;
        const float raw = (tid < NC) ? rwm[c] : rws[c];
        const float win = WIN_MIN_F + WIN_RANGE_F * fast_sigmoid_neg(-raw);
        s_win[tid] = win;
        s_wsi[tid] = (int)(115.0f - win);     // in [51,113]
    }

    // ---- stage series rows [start-NW+t0, +160), then zero pad rows 160..168 ----
    const float4* src4 = (const float4*)(series + (size_t)(start - NW + t0) * NC);
    float4* dst4 = (float4*)s_x;
#pragma unroll
    for (int k = 0; k < 5; ++k) {
        const int j = tid + k * 256;          // exactly 1280 float4s
        dst4[j] = src4[j];
    }
    if (tid < 72) {
        dst4[1280 + tid] = make_float4(0.f, 0.f, 0.f, 0.f);
    }
    __syncthreads();   // S1

    // ---- prefix scan pass 1: thread (c, seg) scans 20 rows into registers ----
    const int c_s  = tid & 31;
    const int seg  = tid >> 5;                 // 0..7
    float l1[20], l2[20];
    {
        float r1 = 0.f, r2 = 0.f;
        const int base = (seg * 20) * NC + c_s;
#pragma unroll
        for (int i = 0; i < 20; ++i) {
            l1[i] = r1; l2[i] = r2;            // exclusive local prefix
            const float xv = s_x[base + i * NC];
            r1 += xv;
            r2 = fmaf(xv, xv, r2);
        }
        s_red[0 * 256 + seg * NC + c_s] = r1;  // segment totals
        s_red[1 * 256 + seg * NC + c_s] = r2;
    }

    // ---- transition weight tables ----
    for (int i = tid; i < 2 * NTR * NC; i += 256) {
        const int c = i & 31;
        const int r = i >> 5;                  // 0..49
        const int tbl = (r >= NTR) ? 1 : 0;
        const int j = r - NTR * tbl;
        const int ws = s_wsi[tbl * NC + c];
        const int w = ws + j;
        float val = 0.f;
        if (w < NW) {
            const float age = (float)(NW - 1 - w);
            val = fast_sigmoid_neg(age - s_win[tbl * NC + c]);
        }
        ((float*)s_wt)[(j * NC + c) * 2 + tbl] = val;
    }
    __syncthreads();   // S2a

    // ---- exclusive scan of 8 segment totals per (table, channel) ----
    if (tid < 64) {
        const int tbl = tid >> 5, c = tid & 31;
        float o = 0.f;
#pragma unroll
        for (int s = 0; s < 8; ++s) {
            const int idx = tbl * 256 + s * NC + c;
            const float t = s_red[idx];
            s_red[idx] = o;
            o += t;
        }
    }
    __syncthreads();   // S2b

    // ---- prefix scan pass 2: write interleaved P = (P1, P2) ----
    {
        const float o1 = s_red[0 * 256 + seg * NC + c_s];
        const float o2 = s_red[1 * 256 + seg * NC + c_s];
#pragma unroll
        for (int i = 0; i < 20; ++i) {
            v2f p; p.x = o1 + l1[i]; p.y = o2 + l2[i];
            s_P[(seg * 20 + i) * NC + c_s] = p;
        }
    }
    __syncthreads();   // S3: P ready

    // ---- main: thread (c, rg) owns 4 rows; 25 weighted taps + prefix tail ----
    const int c  = tid & 31;
    const int rg = tid >> 5;           // 0..7
    const int r0 = rg * 4;
    const int wsm = s_wsi[c];
    const int wss = s_wsi[NC + c];

    float a1[4] = {0.f,0.f,0.f,0.f};
    float a2[4] = {0.f,0.f,0.f,0.f};
    float a3[4] = {0.f,0.f,0.f,0.f};
    float sw1 = 0.f, sw2 = 0.f;

    const int bm_ = (r0 + wsm) * NC + c;
    const int bs_ = (r0 + wss) * NC + c;
    float xm[4], xv[4], qv[4];
#pragma unroll
    for (int k = 0; k < 4; ++k) {
        xm[k] = s_x[bm_ + k * NC];
        const float v = s_x[bs_ + k * NC];
        xv[k] = v; qv[k] = v * v;
    }

#pragma unroll 5
    for (int j = 0; j < NTR; ++j) {
        const v2f wv = s_wt[j * NC + c];   // .x = w1, .y = w2
        sw1 += wv.x; sw2 += wv.y;
#pragma unroll
        for (int k = 0; k < 4; ++k) {
            a1[k] = fmaf(xm[k], wv.x, a1[k]);
            a2[k] = fmaf(xv[k], wv.y, a2[k]);
            a3[k] = fmaf(qv[k], wv.y, a3[k]);
        }
        xm[0] = xm[1]; xm[1] = xm[2]; xm[2] = xm[3];
        xm[3] = s_x[bm_ + (4 + j) * NC];
        xv[0] = xv[1]; xv[1] = xv[2]; xv[2] = xv[3];
        qv[0] = qv[1]; qv[1] = qv[2]; qv[2] = qv[3];
        const float nv = s_x[bs_ + (4 + j) * NC];
        xv[3] = nv; qv[3] = nv * nv;
    }

    const int wsm25 = (wsm + NTR < NW) ? wsm + NTR : NW;
    const int wss25 = (wss + NTR < NW) ? wss + NTR : NW;
    const float s1 = sw1 + (float)(NW - wsm25);
    const float s2 = sw2 + (float)(NW - wss25);
    const float inv1 = __builtin_amdgcn_rcpf(s1);
    const float inv2 = __builtin_amdgcn_rcpf(s2);

    float fm[4], fs[4];                        // live across the grid barrier
    float p0 = 0.f, p1 = 0.f, p2 = 0.f, p3 = 0.f;
#pragma unroll
    for (int k = 0; k < 4; ++k) {
        const int t = r0 + k;
        const v2f pe = s_P[(t + NW) * NC + c];
        const v2f pm = s_P[(t + wsm25) * NC + c];
        const v2f ps = s_P[(t + wss25) * NC + c];
        const float A1 = a1[k] + (pe.x - pm.x);
        const float A2 = a2[k] + (pe.x - ps.x);
        const float A3 = a3[k] + (pe.y - ps.y);
        fm[k] = A1 * inv1;
        const float m2 = A2 * inv2;
        const float var = fmaxf(A3 * inv2 - m2 * m2, 0.f);
        fs[k] = sqrtf(var + 1e-8f);
        p0 += fm[k]; p1 = fmaf(fm[k], fm[k], p1); p2 += fs[k]; p3 = fmaf(fs[k], fs[k], p3);
    }

    s_red[0 * 256 + rg * NC + c] = p0;   // [stat][rg][c]
    s_red[1 * 256 + rg * NC + c] = p1;
    s_red[2 * 256 + rg * NC + c] = p2;
    s_red[3 * 256 + rg * NC + c] = p3;
    __syncthreads();   // S4

    if (tid < 128) {
        const int stat = tid >> 5, cc = tid & 31;
        float s = 0.f;
#pragma unroll
        for (int g = 0; g < 8; ++g) s += s_red[stat * 256 + g * NC + cc];
        partials[blk * (4 * NC) + stat * NC + cc] = s;
    }
    __syncthreads();   // S5: partials stores drained (vmcnt(0) before barrier)

    // ---- device-scope arrive + spin-wait (1 block/CU: all co-resident) ----
    if (tid == 0) {
        __hip_atomic_fetch_add(ctr, 1u, __ATOMIC_ACQ_REL, __HIP_MEMORY_SCOPE_AGENT);
        unsigned int guard = 0;
        while (__hip_atomic_load(ctr, __ATOMIC_ACQUIRE, __HIP_MEMORY_SCOPE_AGENT) < (unsigned)NBLK) {
            __builtin_amdgcn_s_sleep(8);
            if (++guard > 100000000u) break;   // bounded: fail validation, never hang
        }
    }
    __syncthreads();   // S6: all partials visible (acquire done by tid 0, same CU caches)

    // ---- redundant BN reduce: partials [256][128] -> coeffs ----
    {
        const int cell  = tid & 31;
        const int slice = tid >> 5;
        const float4* p4 = (const float4*)partials;
        float4 acc = {0.f, 0.f, 0.f, 0.f};
#pragma unroll 8
        for (int i = 0; i < 32; ++i) {
            const float4 v = p4[(slice * 32 + i) * 32 + cell];
            acc.x += v.x; acc.y += v.y; acc.z += v.z; acc.w += v.w;
        }
        *(float4*)&s_red[(slice * 32 + cell) * 4] = acc;
    }
    __syncthreads();
    if (tid < 32) {
        float4 s = {0.f, 0.f, 0.f, 0.f};
#pragma unroll
        for (int sl = 0; sl < 8; ++sl) {
            const float4 v = ((const float4*)s_red)[sl * 32 + tid];
            s.x += v.x; s.y += v.y; s.z += v.z; s.w += v.w;
        }
        ((float4*)s_sums)[tid] = s;
    }
    __syncthreads();
    if (tid < NC) {
        const float invN = 1.0f / (float)(NB * NT);
        const float mu_m  = s_sums[tid] * invN;
        float var_m = fmaxf(s_sums[32 + tid] * invN - mu_m * mu_m, 0.0f);
        const float A1 = gm[tid] / sqrtf(var_m + 1e-5f);
        const float B1 = bm[tid] - mu_m * A1;
        const float mu_s  = s_sums[64 + tid] * invN;
        float var_s = fmaxf(s_sums[96 + tid] * invN - mu_s * mu_s, 0.0f);
        const float A2 = gs[tid] / sqrtf(var_s + 1e-5f);
        const float B2 = bs[tid] - mu_s * A2;
        s_coef[tid]      = A1;
        s_coef[32 + tid] = B1;
        s_coef[64 + tid] = A2;
        s_coef[96 + tid] = B2;
    }
    __syncthreads();

    // ---- apply BN affine to register fm/fs, write out cols 32..95 ----
    const float A1 = s_coef[c],      B1 = s_coef[32 + c];
    const float A2 = s_coef[64 + c], B2 = s_coef[96 + c];
#pragma unroll
    for (int k = 0; k < 4; ++k) {
        const size_t o = ((size_t)(b * NT + t0 + r0 + k)) * 96;
        out[o + 32 + c] = fmaf(fm[k], A1, B1);
        out[o + 64 + c] = fmaf(fs[k], A2, B2);
    }
}

extern "C" void kernel_launch(void* const* d_in, const int* in_sizes, int n_in,
                              void* d_out, int out_size, void* d_ws, size_t ws_size,
                              hipStream_t stream) {
    const float* x      = (const float*)d_in[0];
    const float* series = (const float*)d_in[1];
    const int*   idx    = (const int*)d_in[2];
    const float* rwm    = (const float*)d_in[3];
    const float* rws    = (const float*)d_in[4];
    const float* gm     = (const float*)d_in[5];
    const float* bm     = (const float*)d_in[6];
    const float* gs     = (const float*)d_in[7];
    const float* bs     = (const float*)d_in[8];
    float* out = (float*)d_out;
    float* ws  = (float*)d_ws;

    float* partials   = ws;
    unsigned int* ctr = (unsigned int*)(ws + NBLK * 4 * NC);

    hipMemsetAsync(ctr, 0, sizeof(unsigned int), stream);
    feat_fused<<<NBLK, 256, 0, stream>>>(x, series, idx, rwm, rws,
                                         gm, bm, gs, bs, partials, ctr, out);
}

// Round 14
// 17.628 us; speedup vs baseline: 1.7366x; 1.7366x over previous
//
#include <hip/hip_runtime.h>
#include <math.h>

#define NB 16          // batch
#define NT 512         // time
#define NC 32          // channels
#define NW 128         // window
#define TILE_T 32
#define NTILES (NT / TILE_T)        // 16
#define NBLK (NB * NTILES)          // 256 blocks -> one per CU
#define NBLK2 128                   // bn_write grid: halves redundant partials traffic
#define NROWS (TILE_T + NW)         // 160 real rows staged
#define PADROWS 169                 // + 9 zero rows (max read row = 168)
#define NTR 25                      // transition taps
#define WIN_MIN_F 2.0f
#define WIN_RANGE_F 62.0f

// ws layout (floats):
#define WS_FMEAN 0
#define WS_FSTD  (NB*NT*NC)
#define WS_PART  (2*NB*NT*NC)       // NBLK * 4 * NC

typedef float v2f __attribute__((ext_vector_type(2)));

__device__ __forceinline__ float fast_sigmoid_neg(float a) {
    // sigmoid(-a) = 1/(1+exp(a))
    return __builtin_amdgcn_rcpf(1.0f + __expf(a));
}

__global__ __launch_bounds__(256) void feat_main(
    const float* __restrict__ x,
    const float* __restrict__ series,
    const int*   __restrict__ indices,
    const float* __restrict__ rwm,
    const float* __restrict__ rws,
    float* __restrict__ f_mean,
    float* __restrict__ f_std,
    float* __restrict__ partials,
    float* __restrict__ out)
{
    // all 2D LDS arrays are [row][c] with 32(floats) or 32(v2f) stride -> bank = f(c) only
    __shared__ __align__(16) float s_x[PADROWS * NC];   // 21.6 KB series tile (+zero pad)
    __shared__ __align__(16) v2f   s_P[NROWS * NC];     // 40 KB prefix sums (P1=x, P2=x^2)
    __shared__ __align__(16) v2f   s_wt[NTR * NC];      // 6.4 KB transition weights (w1,w2)
    __shared__ float s_win[2 * NC];
    __shared__ int   s_wsi[2 * NC];
    __shared__ float s_red[1024];   // scan totals/offsets [2][8][32], then stats [4][8][32]

    const int tid = threadIdx.x;
    const int blk = blockIdx.x;
    const int b   = blk >> 4;
    const int tt  = blk & 15;
    const int t0  = tt * TILE_T;
    const int start = indices[2 * b];

    // ---- BN-independent pass-through: out[:, :, 0:32] = x ----
    {
        const int row = b * NT + t0 + (tid >> 3);
        const int q = tid & 7;
        ((float4*)out)[row * 24 + q] = ((const float4*)x)[row * 8 + q];
    }

    // ---- per-channel window size + transition start ws = int(115 - win) ----
    if (tid < 2 * NC) {
        const int c = tid & 31;
        const float raw = (tid < NC) ? rwm[c] : rws[c];
        const float win = WIN_MIN_F + WIN_RANGE_F * fast_sigmoid_neg(-raw);
        s_win[tid] = win;
        s_wsi[tid] = (int)(115.0f - win);     // in [51,113]
    }

    // ---- stage series rows [start-NW+t0, +160), then zero pad rows 160..168 ----
    const float4* src4 = (const float4*)(series + (size_t)(start - NW + t0) * NC);
    float4* dst4 = (float4*)s_x;
#pragma unroll
    for (int k = 0; k < 5; ++k) {
        const int j = tid + k * 256;          // exactly 1280 float4s
        dst4[j] = src4[j];
    }
    if (tid < 72) {
        dst4[1280 + tid] = make_float4(0.f, 0.f, 0.f, 0.f);
    }
    __syncthreads();   // S1: tile + win/ws visible

    // ---- prefix scan pass 1: thread (c, seg) scans 20 rows into registers ----
    const int c_s  = tid & 31;
    const int seg  = tid >> 5;                 // 0..7
    float l1[20], l2[20];
    {
        float r1 = 0.f, r2 = 0.f;
        const int base = (seg * 20) * NC + c_s;
#pragma unroll
        for (int i = 0; i < 20; ++i) {
            l1[i] = r1; l2[i] = r2;            // exclusive local prefix
            const float xv = s_x[base + i * NC];
            r1 += xv;
            r2 = fmaf(xv, xv, r2);
        }
        s_red[0 * 256 + seg * NC + c_s] = r1;  // segment totals
        s_red[1 * 256 + seg * NC + c_s] = r2;
    }

    // ---- transition weight tables ----
    for (int i = tid; i < 2 * NTR * NC; i += 256) {
        const int c = i & 31;
        const int r = i >> 5;                  // 0..49
        const int tbl = (r >= NTR) ? 1 : 0;
        const int j = r - NTR * tbl;
        const int ws = s_wsi[tbl * NC + c];
        const int w = ws + j;
        float val = 0.f;
        if (w < NW) {
            const float age = (float)(NW - 1 - w);
            val = fast_sigmoid_neg(age - s_win[tbl * NC + c]);
        }
        ((float*)s_wt)[(j * NC + c) * 2 + tbl] = val;
    }
    __syncthreads();   // S2a: totals + tables visible

    // ---- exclusive scan of 8 segment totals per (table, channel) ----
    if (tid < 64) {
        const int tbl = tid >> 5, c = tid & 31;
        float o = 0.f;
#pragma unroll
        for (int s = 0; s < 8; ++s) {
            const int idx = tbl * 256 + s * NC + c;
            const float t = s_red[idx];
            s_red[idx] = o;
            o += t;
        }
    }
    __syncthreads();   // S2b: offsets visible

    // ---- prefix scan pass 2: write interleaved P = (P1, P2) ----
    {
        const float o1 = s_red[0 * 256 + seg * NC + c_s];
        const float o2 = s_red[1 * 256 + seg * NC + c_s];
#pragma unroll
        for (int i = 0; i < 20; ++i) {
            v2f p; p.x = o1 + l1[i]; p.y = o2 + l2[i];
            s_P[(seg * 20 + i) * NC + c_s] = p;
        }
    }
    __syncthreads();   // S3: P ready

    // ---- main: thread (c, rg) owns 4 rows; 25 weighted taps + prefix tail ----
    const int c  = tid & 31;
    const int rg = tid >> 5;           // 0..7
    const int r0 = rg * 4;
    const int wsm = s_wsi[c];
    const int wss = s_wsi[NC + c];

    float a1[4] = {0.f,0.f,0.f,0.f};
    float a2[4] = {0.f,0.f,0.f,0.f};
    float a3[4] = {0.f,0.f,0.f,0.f};
    float sw1 = 0.f, sw2 = 0.f;

    const int bm_ = (r0 + wsm) * NC + c;   // mean-window base
    const int bs_ = (r0 + wss) * NC + c;   // std-window base
    float xm[4], xv[4], qv[4];
#pragma unroll
    for (int k = 0; k < 4; ++k) {
        xm[k] = s_x[bm_ + k * NC];
        const float v = s_x[bs_ + k * NC];
        xv[k] = v; qv[k] = v * v;
    }

#pragma unroll 5
    for (int j = 0; j < NTR; ++j) {
        const v2f wv = s_wt[j * NC + c];   // .x = w1, .y = w2
        sw1 += wv.x; sw2 += wv.y;
#pragma unroll
        for (int k = 0; k < 4; ++k) {
            a1[k] = fmaf(xm[k], wv.x, a1[k]);
            a2[k] = fmaf(xv[k], wv.y, a2[k]);
            a3[k] = fmaf(qv[k], wv.y, a3[k]);
        }
        xm[0] = xm[1]; xm[1] = xm[2]; xm[2] = xm[3];
        xm[3] = s_x[bm_ + (4 + j) * NC];                  // max row 168: padded
        xv[0] = xv[1]; xv[1] = xv[2]; xv[2] = xv[3];
        qv[0] = qv[1]; qv[1] = qv[2]; qv[2] = qv[3];
        const float nv = s_x[bs_ + (4 + j) * NC];
        xv[3] = nv; qv[3] = nv * nv;
    }

    const int wsm25 = (wsm + NTR < NW) ? wsm + NTR : NW;
    const int wss25 = (wss + NTR < NW) ? wss + NTR : NW;
    const float s1 = sw1 + (float)(NW - wsm25);   // + flat-1 tap count
    const float s2 = sw2 + (float)(NW - wss25);
    const float inv1 = __builtin_amdgcn_rcpf(s1);
    const float inv2 = __builtin_amdgcn_rcpf(s2);

    float p0 = 0.f, p1 = 0.f, p2 = 0.f, p3 = 0.f;
#pragma unroll
    for (int k = 0; k < 4; ++k) {
        const int t = r0 + k;
        const v2f pe = s_P[(t + NW) * NC + c];
        const v2f pm = s_P[(t + wsm25) * NC + c];
        const v2f ps = s_P[(t + wss25) * NC + c];
        const float A1 = a1[k] + (pe.x - pm.x);
        const float A2 = a2[k] + (pe.x - ps.x);
        const float A3 = a3[k] + (pe.y - ps.y);
        const float fm = A1 * inv1;
        const float m2 = A2 * inv2;
        const float var = fmaxf(A3 * inv2 - m2 * m2, 0.f);
        const float fs = sqrtf(var + 1e-8f);
        const size_t o = ((size_t)(b * NT + t0 + t)) * NC + c;
        f_mean[o] = fm;
        f_std[o]  = fs;
        p0 += fm; p1 = fmaf(fm, fm, p1); p2 += fs; p3 = fmaf(fs, fs, p3);
    }

    s_red[0 * 256 + rg * NC + c] = p0;   // [stat][rg][c]
    s_red[1 * 256 + rg * NC + c] = p1;
    s_red[2 * 256 + rg * NC + c] = p2;
    s_red[3 * 256 + rg * NC + c] = p3;
    __syncthreads();   // S4

    if (tid < 128) {
        const int stat = tid >> 5, cc = tid & 31;
        float s = 0.f;
#pragma unroll
        for (int g = 0; g < 8; ++g) s += s_red[stat * 256 + g * NC + cc];
        partials[blk * (4 * NC) + stat * NC + cc] = s;
    }
}

// BN-reduce (redundant per block) + float4 writeout. 128 blocks x 256 thr, 64 rows each.
__global__ __launch_bounds__(256) void bn_write(
    const float* __restrict__ f_mean,
    const float* __restrict__ f_std,
    const float* __restrict__ partials,
    const float* __restrict__ gm, const float* __restrict__ bm,
    const float* __restrict__ gs, const float* __restrict__ bs,
    float* __restrict__ out)
{
    __shared__ __align__(16) float s_part[8 * 128];
    __shared__ __align__(16) float s_sums[128];
    __shared__ __align__(16) float s_coef[4 * NC];    // A1,B1,A2,B2

    const int tid = threadIdx.x;

    // phase 1: reduce partials [256][128] -> [128]; 8 slices x 32 float4 cells
    {
        const int cell  = tid & 31;
        const int slice = tid >> 5;
        const float4* p4 = (const float4*)partials;
        float4 acc = {0.f, 0.f, 0.f, 0.f};
#pragma unroll 8
        for (int i = 0; i < 32; ++i) {
            const float4 v = p4[(slice * 32 + i) * 32 + cell];
            acc.x += v.x; acc.y += v.y; acc.z += v.z; acc.w += v.w;
        }
        *(float4*)&s_part[(slice * 32 + cell) * 4] = acc;
    }
    __syncthreads();
    if (tid < 32) {
        float4 s = {0.f, 0.f, 0.f, 0.f};
#pragma unroll
        for (int sl = 0; sl < 8; ++sl) {
            const float4 v = ((const float4*)s_part)[sl * 32 + tid];
            s.x += v.x; s.y += v.y; s.z += v.z; s.w += v.w;
        }
        ((float4*)s_sums)[tid] = s;
    }
    __syncthreads();
    if (tid < NC) {
        const float invN = 1.0f / (float)(NB * NT);
        const float mu_m  = s_sums[tid] * invN;
        float var_m = s_sums[32 + tid] * invN - mu_m * mu_m;
        var_m = fmaxf(var_m, 0.0f);
        const float A1 = gm[tid] / sqrtf(var_m + 1e-5f);
        const float B1 = bm[tid] - mu_m * A1;
        const float mu_s  = s_sums[64 + tid] * invN;
        float var_s = s_sums[96 + tid] * invN - mu_s * mu_s;
        var_s = fmaxf(var_s, 0.0f);
        const float A2 = gs[tid] / sqrtf(var_s + 1e-5f);
        const float B2 = bs[tid] - mu_s * A2;
        s_coef[tid]          = A1;
        s_coef[NC + tid]     = B1;
        s_coef[2 * NC + tid] = A2;
        s_coef[3 * NC + tid] = B2;
    }
    __syncthreads();

    // phase 2: writeout BN cols: 64 rows x 16 float4 = 1024, four coalesced passes
    const float4* fm4 = (const float4*)f_mean;
    const float4* fs4 = (const float4*)f_std;
    const float4* cf4 = (const float4*)s_coef;   // [0..7]=A1 [8..15]=B1 [16..23]=A2 [24..31]=B2
    float4* out4 = (float4*)out;
    const int row0 = blockIdx.x * 64;

#pragma unroll
    for (int k = 0; k < 4; ++k) {
        const int j = tid + k * 256;
        const int r = j >> 4;
        const int q = j & 15;
        const int row = row0 + r;
        float4 v;
        int oq;
        if (q < 8) {
            const float4 f = fm4[row * 8 + q];
            const float4 A = cf4[q], Bv = cf4[8 + q];
            v.x = fmaf(f.x, A.x, Bv.x); v.y = fmaf(f.y, A.y, Bv.y);
            v.z = fmaf(f.z, A.z, Bv.z); v.w = fmaf(f.w, A.w, Bv.w);
            oq = 8 + q;
        } else {
            const int m = q - 8;
            const float4 f = fs4[row * 8 + m];
            const float4 A = cf4[16 + m], Bv = cf4[24 + m];
            v.x = fmaf(f.x, A.x, Bv.x); v.y = fmaf(f.y, A.y, Bv.y);
            v.z = fmaf(f.z, A.z, Bv.z); v.w = fmaf(f.w, A.w, Bv.w);
            oq = 16 + m;
        }
        out4[row * 24 + oq] = v;
    }
}

extern "C" void kernel_launch(void* const* d_in, const int* in_sizes, int n_in,
                              void* d_out, int out_size, void* d_ws, size_t ws_size,
                              hipStream_t stream) {
    const float* x      = (const float*)d_in[0];
    const float* series = (const float*)d_in[1];
    const int*   idx    = (const int*)d_in[2];
    const float* rwm    = (const float*)d_in[3];
    const float* rws    = (const float*)d_in[4];
    const float* gm     = (const float*)d_in[5];
    const float* bm     = (const float*)d_in[6];
    const float* gs     = (const float*)d_in[7];
    const float* bs     = (const float*)d_in[8];
    float* out = (float*)d_out;
    float* ws  = (float*)d_ws;

    float* f_mean   = ws + WS_FMEAN;
    float* f_std    = ws + WS_FSTD;
    float* partials = ws + WS_PART;

    feat_main<<<NBLK, 256, 0, stream>>>(x, series, idx, rwm, rws, f_mean, f_std, partials, out);
    bn_write<<<NBLK2, 256, 0, stream>>>(f_mean, f_std, partials, gm, bm, gs, bs, out);
}

// Round 15
// 15.064 us; speedup vs baseline: 2.0321x; 1.1702x over previous
//
#include <hip/hip_runtime.h>
#include <math.h>

#define NB 16          // batch
#define NT 512         // time
#define NC 32          // channels
#define NW 128         // window
#define TILE_T 32
#define NTILES (NT / TILE_T)        // 16
#define NBLK (NB * NTILES)          // 256 blocks -> one per CU
#define NROWS (TILE_T + NW)         // 160 real rows staged
#define PADROWS 169                 // + 9 zero rows (max read row = 168)
#define NTR 25                      // transition taps
#define WIN_MIN_F 2.0f
#define WIN_RANGE_F 62.0f

// ws layout (floats):
#define WS_FMEAN 0
#define WS_FSTD  (NB*NT*NC)
#define WS_PART  (2*NB*NT*NC)       // NBLK * 4 * NC

typedef float v2f __attribute__((ext_vector_type(2)));

__device__ __forceinline__ float fast_sigmoid_neg(float a) {
    // sigmoid(-a) = 1/(1+exp(a))
    return __builtin_amdgcn_rcpf(1.0f + __expf(a));
}

__global__ __launch_bounds__(256) void feat_main(
    const float* __restrict__ x,
    const float* __restrict__ series,
    const int*   __restrict__ indices,
    const float* __restrict__ rwm,
    const float* __restrict__ rws,
    float* __restrict__ f_mean,
    float* __restrict__ f_std,
    float* __restrict__ partials,
    float* __restrict__ out)
{
    // all 2D LDS arrays are [row][c] with 32(floats) or 32(v2f) stride -> bank = f(c) only
    __shared__ __align__(16) float s_x[PADROWS * NC];   // 21.6 KB series tile (+zero pad)
    __shared__ __align__(16) v2f   s_P[NROWS * NC];     // 40 KB prefix sums (P1=x, P2=x^2)
    __shared__ __align__(16) v2f   s_wt[NTR * NC];      // 6.4 KB transition weights (w1,w2)
    __shared__ float s_win[2 * NC];
    __shared__ int   s_wsi[2 * NC];
    __shared__ float s_red[1024];   // scan totals/offsets [2][8][32], then stats [4][8][32]

    const int tid = threadIdx.x;
    const int blk = blockIdx.x;
    const int b   = blk >> 4;
    const int tt  = blk & 15;
    const int t0  = tt * TILE_T;
    const int start = indices[2 * b];

    // ---- BN-independent pass-through: out[:, :, 0:32] = x ----
    {
        const int row = b * NT + t0 + (tid >> 3);
        const int q = tid & 7;
        ((float4*)out)[row * 24 + q] = ((const float4*)x)[row * 8 + q];
    }

    // ---- per-channel window size + transition start ws = int(115 - win) ----
    if (tid < 2 * NC) {
        const int c = tid & 31;
        const float raw = (tid < NC) ? rwm[c] : rws[c];
        const float win = WIN_MIN_F + WIN_RANGE_F * fast_sigmoid_neg(-raw);
        s_win[tid] = win;
        s_wsi[tid] = (int)(115.0f - win);     // in [51,113]
    }

    // ---- stage series rows [start-NW+t0, +160), then zero pad rows 160..168 ----
    const float4* src4 = (const float4*)(series + (size_t)(start - NW + t0) * NC);
    float4* dst4 = (float4*)s_x;
#pragma unroll
    for (int k = 0; k < 5; ++k) {
        const int j = tid + k * 256;          // exactly 1280 float4s
        dst4[j] = src4[j];
    }
    if (tid < 72) {
        dst4[1280 + tid] = make_float4(0.f, 0.f, 0.f, 0.f);
    }
    __syncthreads();   // S1: tile + win/ws visible

    // ---- prefix scan pass 1: thread (c, seg) scans 20 rows into registers ----
    const int c_s  = tid & 31;
    const int seg  = tid >> 5;                 // 0..7
    float l1[20], l2[20];
    {
        float r1 = 0.f, r2 = 0.f;
        const int base = (seg * 20) * NC + c_s;
#pragma unroll
        for (int i = 0; i < 20; ++i) {
            l1[i] = r1; l2[i] = r2;            // exclusive local prefix
            const float xv = s_x[base + i * NC];
            r1 += xv;
            r2 = fmaf(xv, xv, r2);
        }
        s_red[0 * 256 + seg * NC + c_s] = r1;  // segment totals
        s_red[1 * 256 + seg * NC + c_s] = r2;
    }

    // ---- transition weight tables ----
    for (int i = tid; i < 2 * NTR * NC; i += 256) {
        const int c = i & 31;
        const int r = i >> 5;                  // 0..49
        const int tbl = (r >= NTR) ? 1 : 0;
        const int j = r - NTR * tbl;
        const int ws = s_wsi[tbl * NC + c];
        const int w = ws + j;
        float val = 0.f;
        if (w < NW) {
            const float age = (float)(NW - 1 - w);
            val = fast_sigmoid_neg(age - s_win[tbl * NC + c]);
        }
        ((float*)s_wt)[(j * NC + c) * 2 + tbl] = val;
    }
    __syncthreads();   // S2a: totals + tables visible

    // ---- exclusive scan of 8 segment totals per (table, channel) ----
    if (tid < 64) {
        const int tbl = tid >> 5, c = tid & 31;
        float o = 0.f;
#pragma unroll
        for (int s = 0; s < 8; ++s) {
            const int idx = tbl * 256 + s * NC + c;
            const float t = s_red[idx];
            s_red[idx] = o;
            o += t;
        }
    }
    __syncthreads();   // S2b: offsets visible

    // ---- prefix scan pass 2: write interleaved P = (P1, P2) ----
    {
        const float o1 = s_red[0 * 256 + seg * NC + c_s];
        const float o2 = s_red[1 * 256 + seg * NC + c_s];
#pragma unroll
        for (int i = 0; i < 20; ++i) {
            v2f p; p.x = o1 + l1[i]; p.y = o2 + l2[i];
            s_P[(seg * 20 + i) * NC + c_s] = p;
        }
    }
    __syncthreads();   // S3: P ready

    // ---- main: thread (c, rg) owns 4 rows; 25 weighted taps + prefix tail ----
    const int c  = tid & 31;
    const int rg = tid >> 5;           // 0..7
    const int r0 = rg * 4;
    const int wsm = s_wsi[c];
    const int wss = s_wsi[NC + c];

    float a1[4] = {0.f,0.f,0.f,0.f};
    float a2[4] = {0.f,0.f,0.f,0.f};
    float a3[4] = {0.f,0.f,0.f,0.f};
    float sw1 = 0.f, sw2 = 0.f;

    const int bm_ = (r0 + wsm) * NC + c;   // mean-window base
    const int bs_ = (r0 + wss) * NC + c;   // std-window base
    float xm[4], xv[4], qv[4];
#pragma unroll
    for (int k = 0; k < 4; ++k) {
        xm[k] = s_x[bm_ + k * NC];
        const float v = s_x[bs_ + k * NC];
        xv[k] = v; qv[k] = v * v;
    }

#pragma unroll 5
    for (int j = 0; j < NTR; ++j) {
        const v2f wv = s_wt[j * NC + c];   // .x = w1, .y = w2
        sw1 += wv.x; sw2 += wv.y;
#pragma unroll
        for (int k = 0; k < 4; ++k) {
            a1[k] = fmaf(xm[k], wv.x, a1[k]);
            a2[k] = fmaf(xv[k], wv.y, a2[k]);
            a3[k] = fmaf(qv[k], wv.y, a3[k]);
        }
        xm[0] = xm[1]; xm[1] = xm[2]; xm[2] = xm[3];
        xm[3] = s_x[bm_ + (4 + j) * NC];                  // max row 168: padded
        xv[0] = xv[1]; xv[1] = xv[2]; xv[2] = xv[3];
        qv[0] = qv[1]; qv[1] = qv[2]; qv[2] = qv[3];
        const float nv = s_x[bs_ + (4 + j) * NC];
        xv[3] = nv; qv[3] = nv * nv;
    }

    const int wsm25 = (wsm + NTR < NW) ? wsm + NTR : NW;
    const int wss25 = (wss + NTR < NW) ? wss + NTR : NW;
    const float s1 = sw1 + (float)(NW - wsm25);   // + flat-1 tap count
    const float s2 = sw2 + (float)(NW - wss25);
    const float inv1 = __builtin_amdgcn_rcpf(s1);
    const float inv2 = __builtin_amdgcn_rcpf(s2);

    float p0 = 0.f, p1 = 0.f, p2 = 0.f, p3 = 0.f;
#pragma unroll
    for (int k = 0; k < 4; ++k) {
        const int t = r0 + k;
        const v2f pe = s_P[(t + NW) * NC + c];
        const v2f pm = s_P[(t + wsm25) * NC + c];
        const v2f ps = s_P[(t + wss25) * NC + c];
        const float A1 = a1[k] + (pe.x - pm.x);
        const float A2 = a2[k] + (pe.x - ps.x);
        const float A3 = a3[k] + (pe.y - ps.y);
        const float fm = A1 * inv1;
        const float m2 = A2 * inv2;
        const float var = fmaxf(A3 * inv2 - m2 * m2, 0.f);
        const float fs = sqrtf(var + 1e-8f);
        const size_t o = ((size_t)(b * NT + t0 + t)) * NC + c;
        f_mean[o] = fm;
        f_std[o]  = fs;
        p0 += fm; p1 = fmaf(fm, fm, p1); p2 += fs; p3 = fmaf(fs, fs, p3);
    }

    s_red[0 * 256 + rg * NC + c] = p0;   // [stat][rg][c]
    s_red[1 * 256 + rg * NC + c] = p1;
    s_red[2 * 256 + rg * NC + c] = p2;
    s_red[3 * 256 + rg * NC + c] = p3;
    __syncthreads();   // S4

    if (tid < 128) {
        const int stat = tid >> 5, cc = tid & 31;
        float s = 0.f;
#pragma unroll
        for (int g = 0; g < 8; ++g) s += s_red[stat * 256 + g * NC + cc];
        partials[blk * (4 * NC) + stat * NC + cc] = s;
    }
}

// BN-reduce (redundant per block) + float4 writeout of BN cols. 256 blocks x 256 thr.
__global__ __launch_bounds__(256) void bn_write(
    const float* __restrict__ f_mean,
    const float* __restrict__ f_std,
    const float* __restrict__ partials,
    const float* __restrict__ gm, const float* __restrict__ bm,
    const float* __restrict__ gs, const float* __restrict__ bs,
    float* __restrict__ out)
{
    __shared__ __align__(16) float s_part[8 * 128];
    __shared__ __align__(16) float s_sums[128];
    __shared__ __align__(16) float s_coef[4 * NC];    // A1,B1,A2,B2

    const int tid = threadIdx.x;

    // phase 1: reduce partials [256][128] -> [128]; 8 slices x 32 float4 cells
    {
        const int cell  = tid & 31;
        const int slice = tid >> 5;
        const float4* p4 = (const float4*)partials;
        float4 acc = {0.f, 0.f, 0.f, 0.f};
#pragma unroll 8
        for (int i = 0; i < 32; ++i) {
            const float4 v = p4[(slice * 32 + i) * 32 + cell];
            acc.x += v.x; acc.y += v.y; acc.z += v.z; acc.w += v.w;
        }
        *(float4*)&s_part[(slice * 32 + cell) * 4] = acc;
    }
    __syncthreads();
    if (tid < 32) {
        float4 s = {0.f, 0.f, 0.f, 0.f};
#pragma unroll
        for (int sl = 0; sl < 8; ++sl) {
            const float4 v = ((const float4*)s_part)[sl * 32 + tid];
            s.x += v.x; s.y += v.y; s.z += v.z; s.w += v.w;
        }
        ((float4*)s_sums)[tid] = s;
    }
    __syncthreads();
    if (tid < NC) {
        const float invN = 1.0f / (float)(NB * NT);
        const float mu_m  = s_sums[tid] * invN;
        float var_m = s_sums[32 + tid] * invN - mu_m * mu_m;
        var_m = fmaxf(var_m, 0.0f);
        const float A1 = gm[tid] / sqrtf(var_m + 1e-5f);
        const float B1 = bm[tid] - mu_m * A1;
        const float mu_s  = s_sums[64 + tid] * invN;
        float var_s = s_sums[96 + tid] * invN - mu_s * mu_s;
        var_s = fmaxf(var_s, 0.0f);
        const float A2 = gs[tid] / sqrtf(var_s + 1e-5f);
        const float B2 = bs[tid] - mu_s * A2;
        s_coef[tid]          = A1;
        s_coef[NC + tid]     = B1;
        s_coef[2 * NC + tid] = A2;
        s_coef[3 * NC + tid] = B2;
    }
    __syncthreads();

    // phase 2: writeout BN cols: 32 rows x 16 float4 = 512, two coalesced passes
    const float4* fm4 = (const float4*)f_mean;
    const float4* fs4 = (const float4*)f_std;
    const float4* cf4 = (const float4*)s_coef;   // [0..7]=A1 [8..15]=B1 [16..23]=A2 [24..31]=B2
    float4* out4 = (float4*)out;
    const int row0 = blockIdx.x * 32;

#pragma unroll
    for (int k = 0; k < 2; ++k) {
        const int j = tid + k * 256;
        const int r = j >> 4;
        const int q = j & 15;
        const int row = row0 + r;
        float4 v;
        int oq;
        if (q < 8) {
            const float4 f = fm4[row * 8 + q];
            const float4 A = cf4[q], Bv = cf4[8 + q];
            v.x = fmaf(f.x, A.x, Bv.x); v.y = fmaf(f.y, A.y, Bv.y);
            v.z = fmaf(f.z, A.z, Bv.z); v.w = fmaf(f.w, A.w, Bv.w);
            oq = 8 + q;
        } else {
            const int m = q - 8;
            const float4 f = fs4[row * 8 + m];
            const float4 A = cf4[16 + m], Bv = cf4[24 + m];
            v.x = fmaf(f.x, A.x, Bv.x); v.y = fmaf(f.y, A.y, Bv.y);
            v.z = fmaf(f.z, A.z, Bv.z); v.w = fmaf(f.w, A.w, Bv.w);
            oq = 16 + m;
        }
        out4[row * 24 + oq] = v;
    }
}

extern "C" void kernel_launch(void* const* d_in, const int* in_sizes, int n_in,
                              void* d_out, int out_size, void* d_ws, size_t ws_size,
                              hipStream_t stream) {
    const float* x      = (const float*)d_in[0];
    const float* series = (const float*)d_in[1];
    const int*   idx    = (const int*)d_in[2];
    const float* rwm    = (const float*)d_in[3];
    const float* rws    = (const float*)d_in[4];
    const float* gm     = (const float*)d_in[5];
    const float* bm     = (const float*)d_in[6];
    const float* gs     = (const float*)d_in[7];
    const float* bs     = (const float*)d_in[8];
    float* out = (float*)d_out;
    float* ws  = (float*)d_ws;

    float* f_mean   = ws + WS_FMEAN;
    float* f_std    = ws + WS_FSTD;
    float* partials = ws + WS_PART;

    feat_main<<<NBLK, 256, 0, stream>>>(x, series, idx, rwm, rws, f_mean, f_std, partials, out);
    bn_write<<<NBLK, 256, 0, stream>>>(f_mean, f_std, partials, gm, bm, gs, bs, out);
}